// Round 4
// baseline (888.425 us; speedup 1.0000x reference)
//
#include <hip/hip_runtime.h>
#include <hip/hip_bf16.h>
#include <hip/hip_fp16.h>

typedef __attribute__((ext_vector_type(8))) short bf16x8;
typedef __attribute__((ext_vector_type(4))) float f32x4;

#define DEV __device__ __forceinline__

DEV float ldf(const float* p){ return *p; }
DEV float ldf(const unsigned short* p){ return __uint_as_float(((unsigned)*p) << 16); }
DEV void stout(float* p, float v){ *p = v; }
DEV void stout(unsigned short* p, float v){
  __hip_bfloat16 h = __float2bfloat16(v);
  *p = *reinterpret_cast<unsigned short*>(&h);
}
DEV unsigned short bf16bits(float v){
  __hip_bfloat16 h = __float2bfloat16(v);
  return *reinterpret_cast<unsigned short*>(&h);
}
DEV short bf16s(float v){
  __hip_bfloat16 h = __float2bfloat16(v);
  return *reinterpret_cast<short*>(&h);
}
DEV unsigned short f16bits(float v){
  __half h = __float2half(v);
  return *reinterpret_cast<unsigned short*>(&h);
}
DEV float f16val(unsigned short u){
  __half h = *reinterpret_cast<__half*>(&u);
  return __half2float(h);
}

// ---------------- LayerNorm: one block per 512-elem row, bf16 out ----------
__global__ __launch_bounds__(256) void ln_kernel(const float* __restrict__ in,
    const float* __restrict__ w, const float* __restrict__ bb,
    unsigned short* __restrict__ out)
{
  const int row = blockIdx.x;
  const int tid = threadIdx.x;
  const long base = (long)row * 512;
  float v0 = in[base + tid];
  float v1 = in[base + 256 + tid];
  float s = v0 + v1, ss = v0*v0 + v1*v1;
  #pragma unroll
  for (int o = 32; o > 0; o >>= 1){ s += __shfl_down(s, o); ss += __shfl_down(ss, o); }
  __shared__ float rA[4], rB[4];
  const int wid = tid >> 6, lid = tid & 63;
  if (lid == 0){ rA[wid] = s; rB[wid] = ss; }
  __syncthreads();
  s  = rA[0] + rA[1] + rA[2] + rA[3];
  ss = rB[0] + rB[1] + rB[2] + rB[3];
  float mu  = s * (1.f/512.f);
  float var = ss * (1.f/512.f) - mu*mu;
  float r   = rsqrtf(var + 1e-5f);
  stout(&out[base + tid],       (v0 - mu) * r * w[tid]       + bb[tid]);
  stout(&out[base + 256 + tid], (v1 - mu) * r * w[256 + tid] + bb[256 + tid]);
}

// ---------------- all 4 weight transposes in ONE dispatch ------------------
__global__ __launch_bounds__(256) void weight_transpose_all(
    const float* __restrict__ w_qkv, const float* __restrict__ out_w,
    const float* __restrict__ ffn_w1, const float* __restrict__ ffn_w2,
    unsigned short* __restrict__ wqkvT, unsigned short* __restrict__ outwT,
    unsigned short* __restrict__ w1T, unsigned short* __restrict__ w2T)
{
  int id = blockIdx.x;
  const float* in; unsigned short* out; int ldin, ldout, bx, by;
  if (id < 768)      { in = w_qkv;  out = wqkvT; ldin = 1536; ldout = 512;  bx = id % 48; by = id / 48; }
  else if (id < 1024){ id -= 768;  in = out_w;  out = outwT; ldin = 512;  ldout = 512;  bx = id % 16; by = id / 16; }
  else if (id < 2048){ id -= 1024; in = ffn_w1; out = w1T;   ldin = 2048; ldout = 512;  bx = id % 64; by = id / 64; }
  else               { id -= 2048; in = ffn_w2; out = w2T;   ldin = 512;  ldout = 2048; bx = id % 16; by = id / 16; }
  __shared__ float t[32][33];
  const int n0 = bx*32, k0 = by*32;
  const int c = threadIdx.x & 31, r0 = threadIdx.x >> 5;
  #pragma unroll
  for (int i = 0; i < 4; i++){
    int r = r0 + i*8;
    t[r][c] = in[(long)(k0 + r)*ldin + n0 + c];
  }
  __syncthreads();
  #pragma unroll
  for (int i = 0; i < 4; i++){
    int r = r0 + i*8;
    out[(long)(n0 + r)*ldout + k0 + c] = bf16bits(t[c][r]);
  }
}

// ---------------- MFMA bf16 GEMM, BK=64: C = A @ B'^T ----------------------
// A: M x K bf16 (lda), B: N x K bf16 (ldb)
// EPI: 0 = store acc ; 2 = +bias+res (fp32) ; 3 = gelu(acc+bias)
// VT=1: blocks with n0>=1024 also store acc transposed into vtout (V slice)
template<int MT,int NT,int WGM,int WGN,int WR,int WC,int EPI,typename TOUT,int BDIV,int VT>
__global__ __launch_bounds__(256) void mfma_gemm(
    const unsigned short* __restrict__ A, const unsigned short* __restrict__ B,
    TOUT* __restrict__ C,
    int lda, int ldb, int ldc, int Kd,
    long sA, long sA2, long sB, long sB2, long sC, long sC2,
    const float* __restrict__ bias, const float* __restrict__ res,
    unsigned short* __restrict__ vtout)
{
  const int bz = blockIdx.z;
  A += (long)(bz / BDIV) * sA + (long)(bz % BDIV) * sA2;
  B += (long)(bz / BDIV) * sB + (long)(bz % BDIV) * sB2;
  C += (long)(bz / BDIV) * sC + (long)(bz % BDIV) * sC2;
  if (res) res += (long)(bz / BDIV) * sC + (long)(bz % BDIV) * sC2;
  __shared__ unsigned short As[MT][72];   // 64 k-cols + 8 pad
  __shared__ unsigned short Bs[NT][72];
  const int tid  = threadIdx.x;
  const int lane = tid & 63, wv = tid >> 6;
  const int quad = lane >> 4, l16 = lane & 15;
  const int wm = (wv % WGM) * WR * 16;
  const int wn = (wv / WGM) * WC * 16;
  const int m0 = blockIdx.y * MT, n0 = blockIdx.x * NT;
  f32x4 acc[WR][WC] = {};
  for (int k0 = 0; k0 < Kd; k0 += 64){
    #pragma unroll
    for (int it = 0; it < MT*64/(256*8); ++it){
      int idx = (it*256 + tid) * 8;
      int r = idx >> 6, c = idx & 63;
      *(uint4*)&As[r][c] = *(const uint4*)&A[(long)(m0 + r)*lda + k0 + c];
    }
    #pragma unroll
    for (int it = 0; it < NT*64/(256*8); ++it){
      int idx = (it*256 + tid) * 8;
      int r = idx >> 6, c = idx & 63;
      *(uint4*)&Bs[r][c] = *(const uint4*)&B[(long)(n0 + r)*ldb + k0 + c];
    }
    __syncthreads();
    #pragma unroll
    for (int kk = 0; kk < 2; ++kk){
      bf16x8 af[WR], bfr[WC];
      #pragma unroll
      for (int i = 0; i < WR; i++) af[i]  = *(const bf16x8*)&As[wm + i*16 + l16][kk*32 + quad*8];
      #pragma unroll
      for (int j = 0; j < WC; j++) bfr[j] = *(const bf16x8*)&Bs[wn + j*16 + l16][kk*32 + quad*8];
      #pragma unroll
      for (int i = 0; i < WR; i++)
        #pragma unroll
        for (int j = 0; j < WC; j++)
          acc[i][j] = __builtin_amdgcn_mfma_f32_16x16x32_bf16(af[i], bfr[j], acc[i][j], 0, 0, 0);
    }
    __syncthreads();
  }
  // epilogue: C/D layout col=lane&15, row=quad*4+reg (verified mapping)
  #pragma unroll
  for (int i = 0; i < WR; i++){
    #pragma unroll
    for (int j = 0; j < WC; j++){
      #pragma unroll
      for (int r = 0; r < 4; r++){
        int m = m0 + wm + i*16 + quad*4 + r;
        int n = n0 + wn + j*16 + l16;
        float v = acc[i][j][r];
        long idx = (long)m * ldc + n;
        if (EPI == 0){ stout(&C[idx], v); }
        else if (EPI == 2){ stout(&C[idx], v + bias[n] + res[idx]); }
        else if (EPI == 3){
          v += bias[n];
          v = 0.5f * v * (1.f + erff(v * 0.70710678118f));
          stout(&C[idx], v);
        }
        if (VT && n0 >= 1024){
          long vidx = (long)(m >> 9) * 262144 + (long)(n - 1024) * 512 + (m & 511);
          vtout[vidx] = bf16bits(v);
        }
      }
    }
  }
}

// ---------------- edge bias via MFMA (fp16 out) ----------------------------
__global__ __launch_bounds__(256) void edge_bias_mfma(
    const float* __restrict__ pw,        // [1048576][128]
    const float* __restrict__ edge_w,    // [128][8]
    const float* __restrict__ edge_b,    // [8]
    unsigned short* __restrict__ scores) // fp16 [32][262144]
{
  const int tid  = threadIdx.x;
  const int lane = tid & 63, wv = tid >> 6;
  const int l16  = lane & 15, quad = lane >> 4;
  bf16x8 bw[4];
  #pragma unroll
  for (int s = 0; s < 4; ++s)
    #pragma unroll
    for (int e = 0; e < 8; ++e){
      float v = (l16 < 8) ? edge_w[(s*32 + quad*8 + e)*8 + l16] : 0.f;
      bw[s][e] = bf16s(v);
    }
  const long pair0 = (long)blockIdx.x * 64 + (long)wv * 16;  // wave's 16 pairs
  const float* src = pw + (pair0 + l16) * 128;
  f32x4 acc = {};
  #pragma unroll
  for (int s = 0; s < 4; ++s){
    float4 r0 = *(const float4*)(src + s*32 + quad*8);
    float4 r1 = *(const float4*)(src + s*32 + quad*8 + 4);
    float x[8] = {r0.x,r0.y,r0.z,r0.w,r1.x,r1.y,r1.z,r1.w};
    bf16x8 a;
    #pragma unroll
    for (int e = 0; e < 8; ++e) a[e] = bf16s(x[e]);
    acc = __builtin_amdgcn_mfma_f32_16x16x32_bf16(a, bw[s], acc, 0, 0, 0);
  }
  if (l16 < 8){
    const float eb = edge_b[l16];
    const long b  = pair0 >> 18;
    const long qk = (pair0 & 262143) + quad*4;
    unsigned short pk[4];
    #pragma unroll
    for (int r = 0; r < 4; ++r) pk[r] = f16bits(acc[r] + eb);
    *(uint2*)&scores[(b*8 + l16)*262144 + qk] = *(uint2*)pk;
  }
}

// ---------------- fused attention: logits = 0.125*QK^T + bias; softmax; P@V
// grid (q-tile, h, b) = (8, 8, 4), 256 threads (4 waves, 16 q-rows each).
// Bias tile is staged to LDS with uint4 loads; after softmax the same LDS
// slots are overwritten in place with bf16 P (wave-local rows, no barrier).
__global__ __launch_bounds__(256) void fused_attn(
    const unsigned short* __restrict__ qkv,   // [2048][1536] bf16
    const unsigned short* __restrict__ bias,  // [4][8][512][512] fp16 (= scores)
    const unsigned short* __restrict__ vt,    // [4][512 d][512 k] bf16
    unsigned short* __restrict__ attn_out)    // [2048][512] bf16
{
  __shared__ unsigned short Qs[64][72];    // 64 q x 64 feat
  __shared__ unsigned short Ks[128][72];   // 128 k x 64 feat
  __shared__ unsigned short Vs[64][136];   // 64 d  x 128 k
  __shared__ unsigned short BP[64][144];   // bias fp16 -> P bf16 in place (288B rows, 16B-aligned)
  const int q0 = blockIdx.x * 64;
  const int h  = blockIdx.y;
  const int b  = blockIdx.z;
  const int tid  = threadIdx.x;
  const int lane = tid & 63, w = tid >> 6;
  const int l16  = lane & 15, quad = lane >> 4;

  const unsigned short* Qg = qkv + (long)(b*512 + q0)*1536 + h*64;
  const unsigned short* Kg = qkv + (long)(b*512)*1536 + 512 + h*64;
  const unsigned short* Vg = vt  + (long)b*262144 + (long)(h*64)*512;
  const unsigned short* Bg = bias + ((long)(b*8 + h)*512 + q0)*512;

  // stage Q once: 64x64 bf16
  #pragma unroll
  for (int it = 0; it < 2; ++it){
    int idx = (it*256 + tid)*8; int r = idx >> 6, c = idx & 63;
    *(uint4*)&Qs[r][c] = *(const uint4*)&Qg[(long)r*1536 + c];
  }
  __syncthreads();
  bf16x8 aq[2];
  aq[0] = *(const bf16x8*)&Qs[w*16 + l16][quad*8];
  aq[1] = *(const bf16x8*)&Qs[w*16 + l16][32 + quad*8];

  float m_run[4] = {-1e30f, -1e30f, -1e30f, -1e30f};
  float l_run[4] = {0.f, 0.f, 0.f, 0.f};
  f32x4 on[4] = {};   // O acc: row=quad*4+reg (q), col=l16+16n (d)

  for (int kt = 0; kt < 4; ++kt){
    const int k0 = kt * 128;
    __syncthreads();   // previous tile's Ks/Vs/BP readers done before overwrite
    // stage K-tile: 128 k x 64 feat
    #pragma unroll
    for (int it = 0; it < 4; ++it){
      int idx = (it*256 + tid)*8; int r = idx >> 6, c = idx & 63;
      *(uint4*)&Ks[r][c] = *(const uint4*)&Kg[(long)(k0 + r)*1536 + c];
    }
    // stage V-tile (transposed source): 64 d x 128 k
    #pragma unroll
    for (int it = 0; it < 4; ++it){
      int idx = (it*256 + tid)*8; int r = idx >> 7, c = idx & 127;
      *(uint4*)&Vs[r][c] = *(const uint4*)&Vg[(long)r*512 + k0 + c];
    }
    // stage bias tile 64q x 128k fp16 via wide loads: 4 x uint4 per thread
    #pragma unroll
    for (int it = 0; it < 4; ++it){
      int chunk = it*256 + tid;               // 1024 chunks of 8 halves
      int r = chunk >> 4, c8 = (chunk & 15)*8;
      *(uint4*)&BP[r][c8] = *(const uint4*)&Bg[(long)r*512 + k0 + c8];
    }
    __syncthreads();
    // QK^T: S acc[j] covers keys j*16+l16, rows quad*4+reg
    f32x4 sacc[8] = {};
    #pragma unroll
    for (int j = 0; j < 8; ++j){
      bf16x8 bk0 = *(const bf16x8*)&Ks[j*16 + l16][quad*8];
      bf16x8 bk1 = *(const bf16x8*)&Ks[j*16 + l16][32 + quad*8];
      sacc[j] = __builtin_amdgcn_mfma_f32_16x16x32_bf16(aq[0], bk0, sacc[j], 0, 0, 0);
      sacc[j] = __builtin_amdgcn_mfma_f32_16x16x32_bf16(aq[1], bk1, sacc[j], 0, 0, 0);
    }
    // online softmax per owned row r (row = w*16 + quad*4 + r); P in place
    #pragma unroll
    for (int r = 0; r < 4; ++r){
      const int row = w*16 + quad*4 + r;
      float s[8];
      #pragma unroll
      for (int j = 0; j < 8; ++j)
        s[j] = fmaf(sacc[j][r], 0.125f, f16val(BP[row][l16 + 16*j]));
      float tm = s[0];
      #pragma unroll
      for (int j = 1; j < 8; ++j) tm = fmaxf(tm, s[j]);
      #pragma unroll
      for (int o = 1; o < 16; o <<= 1) tm = fmaxf(tm, __shfl_xor(tm, o));
      float mnew  = fmaxf(m_run[r], tm);
      float alpha = __expf(m_run[r] - mnew);
      m_run[r] = mnew;
      float ps = 0.f;
      #pragma unroll
      for (int j = 0; j < 8; ++j){
        float p = __expf(s[j] - mnew);
        ps += p;
        BP[row][l16 + 16*j] = bf16bits(p);
      }
      #pragma unroll
      for (int o = 1; o < 16; o <<= 1) ps += __shfl_xor(ps, o);
      l_run[r] = l_run[r] * alpha + ps;
      #pragma unroll
      for (int n = 0; n < 4; ++n) on[n][r] *= alpha;
    }
    // PV: BP rows are wave-local (written and read by same wave) -> no barrier
    #pragma unroll
    for (int ks = 0; ks < 4; ++ks){
      bf16x8 pa = *(const bf16x8*)&BP[w*16 + l16][ks*32 + quad*8];
      #pragma unroll
      for (int n = 0; n < 4; ++n){
        bf16x8 bv = *(const bf16x8*)&Vs[n*16 + l16][ks*32 + quad*8];
        on[n] = __builtin_amdgcn_mfma_f32_16x16x32_bf16(pa, bv, on[n], 0, 0, 0);
      }
    }
  }
  // epilogue: normalize by running sum, write bf16 (b,q,h,d) layout
  unsigned short* Og = attn_out + (long)(b*512 + q0)*512 + h*64;
  #pragma unroll
  for (int r = 0; r < 4; ++r){
    float inv = 1.f / l_run[r];
    #pragma unroll
    for (int n = 0; n < 4; ++n)
      Og[(long)(w*16 + quad*4 + r)*512 + n*16 + l16] = bf16bits(on[n][r] * inv);
  }
}

// ---------------------------------------------------------------------------
extern "C" void kernel_launch(void* const* d_in, const int* in_sizes, int n_in,
                              void* d_out, int out_size, void* d_ws, size_t ws_size,
                              hipStream_t stream)
{
  const float* slots    = (const float*)d_in[0];
  const float* pairwise = (const float*)d_in[1];
  const float* ln1_w    = (const float*)d_in[2];
  const float* ln1_b    = (const float*)d_in[3];
  const float* ln2_w    = (const float*)d_in[4];
  const float* ln2_b    = (const float*)d_in[5];
  const float* w_qkv    = (const float*)d_in[6];
  const float* edge_w   = (const float*)d_in[7];
  const float* edge_b   = (const float*)d_in[8];
  const float* out_w    = (const float*)d_in[9];
  const float* out_b    = (const float*)d_in[10];
  const float* ffn_w1   = (const float*)d_in[11];
  const float* ffn_b1   = (const float*)d_in[12];
  const float* ffn_w2   = (const float*)d_in[13];
  const float* ffn_b2   = (const float*)d_in[14];
  float* out = (float*)d_out;

  // ---- workspace layout ----
  float* ws      = (float*)d_ws;
  float* slots2  = ws;                       // 1,048,576 f (4 MB)
  unsigned short* ub = (unsigned short*)(ws + 1048576);
  unsigned short* x_b    = ub;               // 2048x512
  unsigned short* qkv_b  = ub + 1048576;     // 2048x1536
  unsigned short* scores = ub + 4194304;     // 32x512x512 fp16
  unsigned short* vt_b   = ub + 12582912;    // 4x512x512 (V^T, d-major)
  unsigned short* attn_b = ub + 13631488;    // 2048x512
  unsigned short* y_b    = ub + 14680064;    // 2048x512
  unsigned short* h_b    = ub + 15728640;    // 2048x2048
  unsigned short* wqkvT  = ub + 19922944;    // 1536x512
  unsigned short* outwT  = ub + 20709376;    // 512x512
  unsigned short* w1T    = ub + 20971520;    // 2048x512
  unsigned short* w2T    = ub + 22020096;    // 512x2048

  // 1. all weight transposes (fp32 -> bf16, N x K layout), one dispatch
  weight_transpose_all<<<3072, 256, 0, stream>>>(
      w_qkv, out_w, ffn_w1, ffn_w2, wqkvT, outwT, w1T, w2T);
  // 2. x_b = LN1(slots), bf16
  ln_kernel<<<2048, 256, 0, stream>>>(slots, ln1_w, ln1_b, x_b);
  // 3. qkv_b = x_b @ w_qkv  (2048 x 1536 x 512), bf16 out; V third also
  //    stored transposed into vt_b. 384 blocks, BK=64 -> 8 K-iters.
  mfma_gemm<128,64,2,2,4,2,0,unsigned short,1,1><<<dim3(24,16,1), 256, 0, stream>>>(
      x_b, wqkvT, qkv_b, 512, 512, 1536, 512,
      0,0,0,0,0,0, nullptr, nullptr, vt_b);
  // 4. scores = edge bias (fp16, MFMA), layout [b,h,q,k]
  edge_bias_mfma<<<16384, 256, 0, stream>>>(pairwise, edge_w, edge_b, scores);
  // 5. fused attention: attn_b = softmax(0.125*QK^T + bias) @ V
  fused_attn<<<dim3(8,8,4), 256, 0, stream>>>(qkv_b, scores, vt_b, attn_b);
  // 6. slots2 = slots + attn_b @ out_w + out_b  (fp32). 256 blocks, 8 K-iters.
  mfma_gemm<64,64,2,2,2,2,2,float,1,0><<<dim3(8,32,1), 256, 0, stream>>>(
      attn_b, outwT, slots2, 512, 512, 512, 512,
      0,0,0,0,0,0, out_b, slots, nullptr);
  // 7. y_b = LN2(slots2), bf16
  ln_kernel<<<2048, 256, 0, stream>>>(slots2, ln2_w, ln2_b, y_b);
  // 8. h_b = gelu(y_b @ ffn_w1 + ffn_b1)  (2048 x 2048 x 512), bf16. 256 blocks, 8 K-iters.
  mfma_gemm<128,128,2,2,4,4,3,unsigned short,1,0><<<dim3(16,16,1), 256, 0, stream>>>(
      y_b, w1T, h_b, 512, 512, 2048, 512,
      0,0,0,0,0,0, ffn_b1, nullptr, nullptr);
  // 9. out = slots2 + h_b @ ffn_w2 + ffn_b2  (2048 x 512 x 2048), fp32. 256 blocks, 32 K-iters.
  mfma_gemm<64,64,2,2,2,2,2,float,1,0><<<dim3(8,32,1), 256, 0, stream>>>(
      h_b, w2T, out, 2048, 2048, 512, 2048,
      0,0,0,0,0,0, ffn_b2, slots2, nullptr);
}

// Round 5
// 855.527 us; speedup vs baseline: 1.0385x; 1.0385x over previous
//
#include <hip/hip_runtime.h>
#include <hip/hip_bf16.h>
#include <hip/hip_fp16.h>

typedef __attribute__((ext_vector_type(8))) short bf16x8;
typedef __attribute__((ext_vector_type(4))) float f32x4;

#define DEV __device__ __forceinline__

DEV float ldf(const float* p){ return *p; }
DEV float ldf(const unsigned short* p){ return __uint_as_float(((unsigned)*p) << 16); }
DEV void stout(float* p, float v){ *p = v; }
DEV void stout(unsigned short* p, float v){
  __hip_bfloat16 h = __float2bfloat16(v);
  *p = *reinterpret_cast<unsigned short*>(&h);
}
DEV unsigned short bf16bits(float v){
  __hip_bfloat16 h = __float2bfloat16(v);
  return *reinterpret_cast<unsigned short*>(&h);
}
DEV unsigned short f16bits(float v){
  __half h = __float2half(v);
  return *reinterpret_cast<unsigned short*>(&h);
}
DEV float f16val(unsigned short u){
  __half h = *reinterpret_cast<__half*>(&u);
  return __half2float(h);
}

// ---------------- LayerNorm: one block per 512-elem row, bf16 out ----------
__global__ __launch_bounds__(256) void ln_kernel(const float* __restrict__ in,
    const float* __restrict__ w, const float* __restrict__ bb,
    unsigned short* __restrict__ out)
{
  const int row = blockIdx.x;
  const int tid = threadIdx.x;
  const long base = (long)row * 512;
  float v0 = in[base + tid];
  float v1 = in[base + 256 + tid];
  float s = v0 + v1, ss = v0*v0 + v1*v1;
  #pragma unroll
  for (int o = 32; o > 0; o >>= 1){ s += __shfl_down(s, o); ss += __shfl_down(ss, o); }
  __shared__ float rA[4], rB[4];
  const int wid = tid >> 6, lid = tid & 63;
  if (lid == 0){ rA[wid] = s; rB[wid] = ss; }
  __syncthreads();
  s  = rA[0] + rA[1] + rA[2] + rA[3];
  ss = rB[0] + rB[1] + rB[2] + rB[3];
  float mu  = s * (1.f/512.f);
  float var = ss * (1.f/512.f) - mu*mu;
  float r   = rsqrtf(var + 1e-5f);
  stout(&out[base + tid],       (v0 - mu) * r * w[tid]       + bb[tid]);
  stout(&out[base + 256 + tid], (v1 - mu) * r * w[256 + tid] + bb[256 + tid]);
}

// ---------------- all 4 weight transposes in ONE dispatch ------------------
// out[n][k] = in[k][n], fp32 -> bf16.  3072 blocks, segment table on blockIdx.
__global__ __launch_bounds__(256) void weight_transpose_all(
    const float* __restrict__ w_qkv, const float* __restrict__ out_w,
    const float* __restrict__ ffn_w1, const float* __restrict__ ffn_w2,
    unsigned short* __restrict__ wqkvT, unsigned short* __restrict__ outwT,
    unsigned short* __restrict__ w1T, unsigned short* __restrict__ w2T)
{
  int id = blockIdx.x;
  const float* in; unsigned short* out; int ldin, ldout, bx, by;
  if (id < 768)      { in = w_qkv;  out = wqkvT; ldin = 1536; ldout = 512;  bx = id % 48; by = id / 48; }
  else if (id < 1024){ id -= 768;  in = out_w;  out = outwT; ldin = 512;  ldout = 512;  bx = id % 16; by = id / 16; }
  else if (id < 2048){ id -= 1024; in = ffn_w1; out = w1T;   ldin = 2048; ldout = 512;  bx = id % 64; by = id / 64; }
  else               { id -= 2048; in = ffn_w2; out = w2T;   ldin = 512;  ldout = 2048; bx = id % 16; by = id / 16; }
  __shared__ float t[32][33];
  const int n0 = bx*32, k0 = by*32;
  const int c = threadIdx.x & 31, r0 = threadIdx.x >> 5;
  #pragma unroll
  for (int i = 0; i < 4; i++){
    int r = r0 + i*8;
    t[r][c] = in[(long)(k0 + r)*ldin + n0 + c];
  }
  __syncthreads();
  #pragma unroll
  for (int i = 0; i < 4; i++){
    int r = r0 + i*8;
    out[(long)(n0 + r)*ldout + k0 + c] = bf16bits(t[c][r]);
  }
}

// ---------------- MFMA bf16 GEMM: C = A @ B'^T (both operands row x K) -----
// A: M x K bf16 (lda), B: N x K bf16 (ldb)  [i.e. B' is the N-major operand]
// EPI: 0 = store acc ; 2 = +bias+res (fp32) ; 3 = gelu(acc+bias)
// VT=1 (with EPI=0): blocks with n0>=1024 also store acc transposed into
//   vtout[b][n-1024][m&511]  (fused V-transpose for attention)
template<int MT,int NT,int WGM,int WGN,int WR,int WC,int EPI,typename TOUT,int BDIV,int VT>
__global__ __launch_bounds__(256) void mfma_gemm(
    const unsigned short* __restrict__ A, const unsigned short* __restrict__ B,
    TOUT* __restrict__ C,
    int lda, int ldb, int ldc, int Kd,
    long sA, long sA2, long sB, long sB2, long sC, long sC2,
    const float* __restrict__ bias, const float* __restrict__ res,
    unsigned short* __restrict__ vtout)
{
  const int bz = blockIdx.z;
  A += (long)(bz / BDIV) * sA + (long)(bz % BDIV) * sA2;
  B += (long)(bz / BDIV) * sB + (long)(bz % BDIV) * sB2;
  C += (long)(bz / BDIV) * sC + (long)(bz % BDIV) * sC2;
  if (res) res += (long)(bz / BDIV) * sC + (long)(bz % BDIV) * sC2;
  __shared__ unsigned short As[MT][40];   // +8 pad: 2-way LDS banks (free)
  __shared__ unsigned short Bs[NT][40];
  const int tid  = threadIdx.x;
  const int lane = tid & 63, wv = tid >> 6;
  const int quad = lane >> 4, l16 = lane & 15;
  const int wm = (wv % WGM) * WR * 16;
  const int wn = (wv / WGM) * WC * 16;
  const int m0 = blockIdx.y * MT, n0 = blockIdx.x * NT;
  f32x4 acc[WR][WC] = {};
  for (int k0 = 0; k0 < Kd; k0 += 32){
    #pragma unroll
    for (int it = 0; it < MT*32/(256*8); ++it){
      int idx = (it*256 + tid) * 8;
      int r = idx >> 5, c = idx & 31;
      *(uint4*)&As[r][c] = *(const uint4*)&A[(long)(m0 + r)*lda + k0 + c];
    }
    #pragma unroll
    for (int it = 0; it < NT*32/(256*8); ++it){
      int idx = (it*256 + tid) * 8;
      int r = idx >> 5, c = idx & 31;
      *(uint4*)&Bs[r][c] = *(const uint4*)&B[(long)(n0 + r)*ldb + k0 + c];
    }
    __syncthreads();
    bf16x8 af[WR], bfr[WC];
    #pragma unroll
    for (int i = 0; i < WR; i++) af[i]  = *(const bf16x8*)&As[wm + i*16 + l16][quad*8];
    #pragma unroll
    for (int j = 0; j < WC; j++) bfr[j] = *(const bf16x8*)&Bs[wn + j*16 + l16][quad*8];
    #pragma unroll
    for (int i = 0; i < WR; i++)
      #pragma unroll
      for (int j = 0; j < WC; j++)
        acc[i][j] = __builtin_amdgcn_mfma_f32_16x16x32_bf16(af[i], bfr[j], acc[i][j], 0, 0, 0);
    __syncthreads();
  }
  // epilogue: C/D layout col=lane&15, row=quad*4+reg (verified mapping)
  #pragma unroll
  for (int i = 0; i < WR; i++){
    #pragma unroll
    for (int j = 0; j < WC; j++){
      #pragma unroll
      for (int r = 0; r < 4; r++){
        int m = m0 + wm + i*16 + quad*4 + r;
        int n = n0 + wn + j*16 + l16;
        float v = acc[i][j][r];
        long idx = (long)m * ldc + n;
        if (EPI == 0){ stout(&C[idx], v); }
        else if (EPI == 2){ stout(&C[idx], v + bias[n] + res[idx]); }
        else if (EPI == 3){
          v += bias[n];
          v = 0.5f * v * (1.f + erff(v * 0.70710678118f));
          stout(&C[idx], v);
        }
        if (VT && n0 >= 1024){
          long vidx = (long)(m >> 9) * 262144 + (long)(n - 1024) * 512 + (m & 511);
          vtout[vidx] = bf16bits(v);
        }
      }
    }
  }
}

// ---------------- edge bias (fp16 out): scores[b,h,q,k] = pw[b,q,k,:]·ew[:,h]+eb[h]
__global__ __launch_bounds__(256) void edge_bias_kernel(
    const float* __restrict__ pw,
    const float* __restrict__ edge_w,
    const float* __restrict__ edge_b,
    unsigned short* __restrict__ scores)
{
  const int tid  = threadIdx.x;
  const int lane = tid & 63;
  const int wid  = tid >> 6;
  const int sub  = lane & 15;
  const int quad = lane >> 4;
  float ew[8][8];
  #pragma unroll
  for (int j = 0; j < 8; j++)
    #pragma unroll
    for (int h = 0; h < 8; h++)
      ew[j][h] = edge_w[(sub*8 + j)*8 + h];
  const int b3 = (sub >> 3) & 1, b2_ = (sub >> 2) & 1, b1 = (sub >> 1) & 1;
  const int myh = b3*4 + b2_*2 + b1;
  const float ebh = edge_b[myh];
  const long total = 1048576;  // 4*512*512 pairs
  for (long base = (long)blockIdx.x * 16; base < total; base += (long)gridDim.x * 16){
    long pair = base + wid*4 + quad;
    const float* src = pw + pair * 128 + sub * 8;
    float4 r0 = *reinterpret_cast<const float4*>(src);
    float4 r1 = *reinterpret_cast<const float4*>(src + 4);
    float x[8] = {r0.x, r0.y, r0.z, r0.w, r1.x, r1.y, r1.z, r1.w};
    float acc[8] = {0,0,0,0,0,0,0,0};
    #pragma unroll
    for (int j = 0; j < 8; j++)
      #pragma unroll
      for (int h = 0; h < 8; h++)
        acc[h] += x[j] * ew[j][h];
    float t[4];
    #pragma unroll
    for (int i = 0; i < 4; i++){
      float send = b3 ? acc[i] : acc[i+4];
      float keep = b3 ? acc[i+4] : acc[i];
      t[i] = keep + __shfl_xor(send, 8);
    }
    float u[2];
    #pragma unroll
    for (int i = 0; i < 2; i++){
      float send = b2_ ? t[i] : t[i+2];
      float keep = b2_ ? t[i+2] : t[i];
      u[i] = keep + __shfl_xor(send, 4);
    }
    float send = b1 ? u[0] : u[1];
    float keep = b1 ? u[1] : u[0];
    float val = keep + __shfl_xor(send, 2);
    val += __shfl_xor(val, 1);
    if ((sub & 1) == 0){
      long b  = pair >> 18;
      long qk = pair & 262143;
      scores[(b*8 + myh) * 262144 + qk] = f16bits(val + ebh);
    }
  }
}

// ---------------- fused attention: logits = 0.125*QK^T + bias; softmax; P@V
// grid (q-tile, h, b) = (8, 8, 4), 256 threads (4 waves, 16 q-rows each).
__global__ __launch_bounds__(256) void fused_attn(
    const unsigned short* __restrict__ qkv,   // [2048][1536] bf16
    const unsigned short* __restrict__ bias,  // [4][8][512][512] fp16 (= scores)
    const unsigned short* __restrict__ vt,    // [4][512 d][512 k] bf16
    unsigned short* __restrict__ attn_out)    // [2048][512] bf16
{
  __shared__ unsigned short Qs[64][72];    // 64 q x 64 feat, +8 pad
  __shared__ unsigned short Ks[128][72];   // 128 k x 64 feat
  __shared__ unsigned short Vs[64][136];   // 64 d  x 128 k
  __shared__ unsigned short Ps[64][136];   // 64 q  x 128 k (bf16 probs)
  const int q0 = blockIdx.x * 64;
  const int h  = blockIdx.y;
  const int b  = blockIdx.z;
  const int tid  = threadIdx.x;
  const int lane = tid & 63, w = tid >> 6;
  const int l16  = lane & 15, quad = lane >> 4;

  const unsigned short* Qg = qkv + (long)(b*512 + q0)*1536 + h*64;
  const unsigned short* Kg = qkv + (long)(b*512)*1536 + 512 + h*64;
  const unsigned short* Vg = vt  + (long)b*262144 + (long)(h*64)*512;
  const unsigned short* Bg = bias + ((long)(b*8 + h)*512 + q0)*512;

  // stage Q once: 64x64 bf16
  #pragma unroll
  for (int it = 0; it < 2; ++it){
    int idx = (it*256 + tid)*8; int r = idx >> 6, c = idx & 63;
    *(uint4*)&Qs[r][c] = *(const uint4*)&Qg[(long)r*1536 + c];
  }
  __syncthreads();
  bf16x8 aq[2];
  aq[0] = *(const bf16x8*)&Qs[w*16 + l16][quad*8];
  aq[1] = *(const bf16x8*)&Qs[w*16 + l16][32 + quad*8];

  float m_run[4] = {-1e30f, -1e30f, -1e30f, -1e30f};
  float l_run[4] = {0.f, 0.f, 0.f, 0.f};
  f32x4 on[4] = {};   // O acc: row=quad*4+reg (q), col=l16+16n (d)

  for (int kt = 0; kt < 4; ++kt){
    const int k0 = kt * 128;
    __syncthreads();   // previous tile's Ks/Vs readers done before overwrite
    // stage K-tile: 128 k x 64 feat
    #pragma unroll
    for (int it = 0; it < 4; ++it){
      int idx = (it*256 + tid)*8; int r = idx >> 6, c = idx & 63;
      *(uint4*)&Ks[r][c] = *(const uint4*)&Kg[(long)(k0 + r)*1536 + c];
    }
    // stage V-tile (transposed source): 64 d x 128 k
    #pragma unroll
    for (int it = 0; it < 4; ++it){
      int idx = (it*256 + tid)*8; int r = idx >> 7, c = idx & 127;
      *(uint4*)&Vs[r][c] = *(const uint4*)&Vg[(long)r*512 + k0 + c];
    }
    // bias loads (independent of LDS): fp16, lanes form 32B segments
    float bb[4][8];
    #pragma unroll
    for (int r = 0; r < 4; ++r){
      const unsigned short* bp = Bg + (long)(w*16 + quad*4 + r)*512 + k0 + l16;
      #pragma unroll
      for (int j = 0; j < 8; ++j) bb[r][j] = f16val(bp[16*j]);
    }
    __syncthreads();
    // QK^T: S acc[j] covers keys j*16+l16, rows quad*4+reg
    f32x4 sacc[8] = {};
    #pragma unroll
    for (int j = 0; j < 8; ++j){
      bf16x8 bk0 = *(const bf16x8*)&Ks[j*16 + l16][quad*8];
      bf16x8 bk1 = *(const bf16x8*)&Ks[j*16 + l16][32 + quad*8];
      sacc[j] = __builtin_amdgcn_mfma_f32_16x16x32_bf16(aq[0], bk0, sacc[j], 0, 0, 0);
      sacc[j] = __builtin_amdgcn_mfma_f32_16x16x32_bf16(aq[1], bk1, sacc[j], 0, 0, 0);
    }
    // online softmax per owned row r (row = w*16 + quad*4 + r)
    #pragma unroll
    for (int r = 0; r < 4; ++r){
      float s[8];
      #pragma unroll
      for (int j = 0; j < 8; ++j) s[j] = fmaf(sacc[j][r], 0.125f, bb[r][j]);
      float tm = s[0];
      #pragma unroll
      for (int j = 1; j < 8; ++j) tm = fmaxf(tm, s[j]);
      #pragma unroll
      for (int o = 1; o < 16; o <<= 1) tm = fmaxf(tm, __shfl_xor(tm, o));
      float mnew  = fmaxf(m_run[r], tm);
      float alpha = __expf(m_run[r] - mnew);
      m_run[r] = mnew;
      float ps = 0.f;
      #pragma unroll
      for (int j = 0; j < 8; ++j){
        float p = __expf(s[j] - mnew);
        ps += p;
        Ps[w*16 + quad*4 + r][l16 + 16*j] = bf16bits(p);
      }
      #pragma unroll
      for (int o = 1; o < 16; o <<= 1) ps += __shfl_xor(ps, o);
      l_run[r] = l_run[r] * alpha + ps;
      #pragma unroll
      for (int n = 0; n < 4; ++n) on[n][r] *= alpha;
    }
    // PV: Ps rows are wave-local (written and read by same wave) -> no barrier
    #pragma unroll
    for (int ks = 0; ks < 4; ++ks){
      bf16x8 pa = *(const bf16x8*)&Ps[w*16 + l16][ks*32 + quad*8];
      #pragma unroll
      for (int n = 0; n < 4; ++n){
        bf16x8 bv = *(const bf16x8*)&Vs[n*16 + l16][ks*32 + quad*8];
        on[n] = __builtin_amdgcn_mfma_f32_16x16x32_bf16(pa, bv, on[n], 0, 0, 0);
      }
    }
  }
  // epilogue: normalize by running sum, write bf16 (b,q,h,d) layout
  unsigned short* Og = attn_out + (long)(b*512 + q0)*512 + h*64;
  #pragma unroll
  for (int r = 0; r < 4; ++r){
    float inv = 1.f / l_run[r];
    #pragma unroll
    for (int n = 0; n < 4; ++n)
      Og[(long)(w*16 + quad*4 + r)*512 + n*16 + l16] = bf16bits(on[n][r] * inv);
  }
}

// ---------------------------------------------------------------------------
extern "C" void kernel_launch(void* const* d_in, const int* in_sizes, int n_in,
                              void* d_out, int out_size, void* d_ws, size_t ws_size,
                              hipStream_t stream)
{
  const float* slots    = (const float*)d_in[0];
  const float* pairwise = (const float*)d_in[1];
  const float* ln1_w    = (const float*)d_in[2];
  const float* ln1_b    = (const float*)d_in[3];
  const float* ln2_w    = (const float*)d_in[4];
  const float* ln2_b    = (const float*)d_in[5];
  const float* w_qkv    = (const float*)d_in[6];
  const float* edge_w   = (const float*)d_in[7];
  const float* edge_b   = (const float*)d_in[8];
  const float* out_w    = (const float*)d_in[9];
  const float* out_b    = (const float*)d_in[10];
  const float* ffn_w1   = (const float*)d_in[11];
  const float* ffn_b1   = (const float*)d_in[12];
  const float* ffn_w2   = (const float*)d_in[13];
  const float* ffn_b2   = (const float*)d_in[14];
  float* out = (float*)d_out;

  // ---- workspace layout ----
  float* ws      = (float*)d_ws;
  float* slots2  = ws;                       // 1,048,576 f (4 MB)
  unsigned short* ub = (unsigned short*)(ws + 1048576);
  unsigned short* x_b    = ub;               // 2048x512
  unsigned short* qkv_b  = ub + 1048576;     // 2048x1536
  unsigned short* scores = ub + 4194304;     // 32x512x512 fp16
  unsigned short* vt_b   = ub + 12582912;    // 4x512x512 (V^T, d-major)
  unsigned short* attn_b = ub + 13631488;    // 2048x512
  unsigned short* y_b    = ub + 14680064;    // 2048x512
  unsigned short* h_b    = ub + 15728640;    // 2048x2048
  unsigned short* wqkvT  = ub + 19922944;    // 1536x512
  unsigned short* outwT  = ub + 20709376;    // 512x512
  unsigned short* w1T    = ub + 20971520;    // 2048x512
  unsigned short* w2T    = ub + 22020096;    // 512x2048

  // 1. all weight transposes (fp32 -> bf16, N x K layout), one dispatch
  weight_transpose_all<<<3072, 256, 0, stream>>>(
      w_qkv, out_w, ffn_w1, ffn_w2, wqkvT, outwT, w1T, w2T);
  // 2. x_b = LN1(slots), bf16
  ln_kernel<<<2048, 256, 0, stream>>>(slots, ln1_w, ln1_b, x_b);
  // 3. qkv_b = x_b @ w_qkv  (2048 x 1536 x 512), bf16 out; V third also
  //    stored transposed into vt_b (fused V-transpose)
  mfma_gemm<128,128,2,2,4,4,0,unsigned short,1,1><<<dim3(12,16,1), 256, 0, stream>>>(
      x_b, wqkvT, qkv_b, 512, 512, 1536, 512,
      0,0,0,0,0,0, nullptr, nullptr, vt_b);
  // 4. scores = edge bias (fp16), layout [b,h,q,k]
  edge_bias_kernel<<<8192, 256, 0, stream>>>(pairwise, edge_w, edge_b, scores);
  // 5. fused attention: attn_b = softmax(0.125*QK^T + bias) @ V
  fused_attn<<<dim3(8,8,4), 256, 0, stream>>>(qkv_b, scores, vt_b, attn_b);
  // 6. slots2 = slots + attn_b @ out_w + out_b  (fp32)
  mfma_gemm<64,128,1,4,4,2,2,float,1,0><<<dim3(4,32,1), 256, 0, stream>>>(
      attn_b, outwT, slots2, 512, 512, 512, 512,
      0,0,0,0,0,0, out_b, slots, nullptr);
  // 7. y_b = LN2(slots2), bf16
  ln_kernel<<<2048, 256, 0, stream>>>(slots2, ln2_w, ln2_b, y_b);
  // 8. h_b = gelu(y_b @ ffn_w1 + ffn_b1)  (2048 x 2048 x 512), bf16
  mfma_gemm<128,128,2,2,4,4,3,unsigned short,1,0><<<dim3(16,16,1), 256, 0, stream>>>(
      y_b, w1T, h_b, 512, 512, 2048, 512,
      0,0,0,0,0,0, ffn_b1, nullptr, nullptr);
  // 9. out = slots2 + h_b @ ffn_w2 + ffn_b2  (2048 x 512 x 2048), fp32
  mfma_gemm<64,128,1,4,4,2,2,float,1,0><<<dim3(4,32,1), 256, 0, stream>>>(
      h_b, w2T, out, 2048, 2048, 512, 2048,
      0,0,0,0,0,0, ffn_b2, slots2, nullptr);
}